// Round 3
// baseline (192.272 us; speedup 1.0000x reference)
//
#include <hip/hip_runtime.h>
#include <stdint.h>

#define CIN 128
#define COUT 256
#define NIN 400000
#define MOUT 100000
#define KOFFS 8
#define EPSV 1e-4f
#define BM 256
#define BK 64
#define NT 16        // K-steps: 8 offsets * 128 ch / 64
#define THREADS 512

typedef __attribute__((ext_vector_type(8))) short short8;
typedef __attribute__((ext_vector_type(4))) float f32x4;
typedef __attribute__((address_space(3))) uint32_t lds_u32;
typedef const __attribute__((address_space(1))) uint32_t glb_u32;

__device__ __forceinline__ unsigned f2bf_u(float f) {
  union { float f; unsigned u; } v; v.f = f;
  return (v.u + 0x7FFFu + ((v.u >> 16) & 1u)) >> 16;  // RNE bf16
}

// ---------------------------------------------------------------------------
// Kernel 0: W[k][c][n] fp32 -> Wt_swz, 16 x 32KB blocks, inverse-swizzled so
// conv reads at byte n*128 + (inner ^ ((n&7)<<4)). Zeroes BN accumulators.
// ---------------------------------------------------------------------------
__global__ void prep_kernel(const float* __restrict__ W,
                            unsigned short* __restrict__ Wt,
                            float* __restrict__ gstat) {
  const int s = blockIdx.x;   // 0..15
  const int n = threadIdx.x;  // 0..255
  if (s == 0) { gstat[n] = 0.f; gstat[n + 256] = 0.f; }
  const int koff = s >> 1;
  const int cbase = (s & 1) * 64;
  const float* Wk = W + koff * (CIN * COUT);
  unsigned short row[64];
  #pragma unroll
  for (int c = 0; c < 64; ++c)
    row[c] = (unsigned short)f2bf_u(Wk[(cbase + c) * COUT + n]);
  uint4* dst = (uint4*)((char*)Wt + s * 32768 + n * 128);
  #pragma unroll
  for (int j = 0; j < 8; ++j) {
    const unsigned short* p = &row[(j ^ (n & 7)) * 8];
    uint4 v;
    v.x = (unsigned)p[0] | ((unsigned)p[1] << 16);
    v.y = (unsigned)p[2] | ((unsigned)p[3] << 16);
    v.z = (unsigned)p[4] | ((unsigned)p[5] << 16);
    v.w = (unsigned)p[6] | ((unsigned)p[7] << 16);
    dst[j] = v;
  }
}

// ---------------------------------------------------------------------------
// Kernel 1: gather-GEMM conv, 256x256, 8 waves, pinned 4-phase pipeline.
// ---------------------------------------------------------------------------
__global__ __launch_bounds__(THREADS, 2) void conv_kernel(
    const float* __restrict__ feats,
    const unsigned short* __restrict__ Wt,
    const int* __restrict__ gidx,
    unsigned short* __restrict__ rawout,   // bf16 raw path (or null)
    float* __restrict__ out32,             // f32 fallback path (or null)
    float* __restrict__ gstat) {
  __shared__ unsigned short Ab[2][BM * BK];    // 2 x 32 KB
  __shared__ unsigned short Bb[2][COUT * BK];  // 2 x 32 KB
  __shared__ int IDX[BM * KOFFS];              // 8 KB

  const int tid = threadIdx.x;
  const int lane = tid & 63;
  const int wave = tid >> 6;
  const int wm = wave >> 2;
  const int wn = wave & 3;
  const int row16 = lane & 15;
  const int quad = lane >> 4;
  const long base_m = (long)blockIdx.x * BM;

  for (int i = tid; i < BM * KOFFS; i += THREADS) {
    long m = base_m + (i >> 3);
    IDX[i] = (m < MOUT) ? gidx[m * KOFFS + (i & 7)] : NIN;
  }
  __syncthreads();

  const int ar = tid >> 4;   // 32 rows per pass
  const int ac = tid & 15;   // 16B chunk within 64-ch slice

  float4 st[4];
  int sidx[4];

  // --- staging helpers (branchless: clamp + mask at write) ---
  auto A_LOADh = [&](int s, int h) {
    const int koff = s >> 1;
    const int cb4 = ((s & 1) << 6) + (ac << 2);
    #pragma unroll
    for (int p = 0; p < 4; ++p) {
      int r = (h * 4 + p) * 32 + ar;
      int idx = IDX[r * KOFFS + koff];
      sidx[p] = idx;
      int cl = idx < NIN ? idx : NIN - 1;   // inactive -> L1-broadcast row
      st[p] = *(const float4*)(feats + (long)cl * CIN + cb4);
    }
  };
  auto A_WRITEh = [&](int b, int h) {
    #pragma unroll
    for (int p = 0; p < 4; ++p) {
      int r = (h * 4 + p) * 32 + ar;
      uint2 pk;
      pk.x = f2bf_u(st[p].x) | (f2bf_u(st[p].y) << 16);
      pk.y = f2bf_u(st[p].z) | (f2bf_u(st[p].w) << 16);
      if (sidx[p] >= NIN) { pk.x = 0u; pk.y = 0u; }   // cndmask, no branch
      *(uint2*)((char*)Ab[b] + r * 128 + ((ac << 3) ^ ((r & 7) << 4))) = pk;
    }
  };
  auto B_STAGE = [&](int s, int b) {
    const char* src = (const char*)Wt + s * 32768 + (wave << 12) + (lane << 4);
    char* dstb = (char*)Bb[b] + (wave << 12) + (lane << 4);
    #pragma unroll
    for (int i = 0; i < 4; ++i)
      __builtin_amdgcn_global_load_lds((glb_u32*)(src + i * 1024),
                                       (lds_u32*)(dstb + i * 1024), 16, 0, 0);
  };

  f32x4 acc[8][4];
  #pragma unroll
  for (int mi = 0; mi < 8; ++mi)
    #pragma unroll
    for (int ni = 0; ni < 4; ++ni)
      acc[mi][ni] = (f32x4){0.f, 0.f, 0.f, 0.f};

  auto MMA_ks = [&](int b, int ks) {
    short8 af[8], bfr[4];
    const int inner = (ks << 6) + (quad << 4);
    #pragma unroll
    for (int mi = 0; mi < 8; ++mi) {
      int r = (wm << 7) + (mi << 4) + row16;
      af[mi] = *(const short8*)((const char*)Ab[b] + r * 128 +
                                (inner ^ ((r & 7) << 4)));
    }
    #pragma unroll
    for (int ni = 0; ni < 4; ++ni) {
      int n = (wn << 6) + (ni << 4) + row16;
      bfr[ni] = *(const short8*)((const char*)Bb[b] + n * 128 +
                                 (inner ^ ((n & 7) << 4)));
    }
    __builtin_amdgcn_s_setprio(1);
    #pragma unroll
    for (int mi = 0; mi < 8; ++mi)
      #pragma unroll
      for (int ni = 0; ni < 4; ++ni)
        acc[mi][ni] = __builtin_amdgcn_mfma_f32_16x16x32_bf16(
            af[mi], bfr[ni], acc[mi][ni], 0, 0, 0);
    __builtin_amdgcn_s_setprio(0);
  };

  // --- prologue: stage step 0 into buffer 0 ---
  A_LOADh(0, 0); A_WRITEh(0, 0);
  A_LOADh(0, 1); A_WRITEh(0, 1);
  B_STAGE(0, 0);
  __syncthreads();

  // --- main loop: pinned 4-phase per K-step, one barrier per step ---
  int cb = 0;
  for (int s = 0; s < NT - 1; ++s) {
    A_LOADh(s + 1, 0);            // phase A: issue gathers + B prefetch
    B_STAGE(s + 1, cb ^ 1);
    __builtin_amdgcn_sched_barrier(0);
    MMA_ks(cb, 0);                // phase B: 32 MFMA (ks0) hides load latency
    __builtin_amdgcn_sched_barrier(0);
    A_WRITEh(cb ^ 1, 0);          // phase C: vmcnt(4) + cvt + ds_write; issue h1
    A_LOADh(s + 1, 1);
    __builtin_amdgcn_sched_barrier(0);
    MMA_ks(cb, 1);                // phase D: 32 MFMA (ks1)
    __builtin_amdgcn_sched_barrier(0);
    A_WRITEh(cb ^ 1, 1);
    __syncthreads();              // drain: only old L2-resident B loads
    cb ^= 1;
  }
  MMA_ks(cb, 0);                  // peeled last step, no staging
  MMA_ks(cb, 1);

  // --- epilogue: raw store (bf16 or f32) + per-channel sum/sumsq ---
  float sm[4], sq[4];
  #pragma unroll
  for (int ni = 0; ni < 4; ++ni) { sm[ni] = 0.f; sq[ni] = 0.f; }
  #pragma unroll
  for (int mi = 0; mi < 8; ++mi) {
    #pragma unroll
    for (int rr = 0; rr < 4; ++rr) {
      long m = base_m + (wm << 7) + (mi << 4) + (quad << 2) + rr;
      bool ok = (m < MOUT);
      #pragma unroll
      for (int ni = 0; ni < 4; ++ni) {
        float v = acc[mi][ni][rr];
        int n = (wn << 6) + (ni << 4) + row16;
        if (ok) {
          if (rawout) rawout[m * COUT + n] = (unsigned short)f2bf_u(v);
          else        out32[m * COUT + n] = v;
        }
        sm[ni] += v;
        sq[ni] += v * v;
      }
    }
  }
  #pragma unroll
  for (int ni = 0; ni < 4; ++ni) {
    sm[ni] += __shfl_xor(sm[ni], 16);
    sm[ni] += __shfl_xor(sm[ni], 32);
    sq[ni] += __shfl_xor(sq[ni], 16);
    sq[ni] += __shfl_xor(sq[ni], 32);
  }
  if (quad == 0) {
    #pragma unroll
    for (int ni = 0; ni < 4; ++ni) {
      int n = (wn << 6) + (ni << 4) + row16;
      atomicAdd(&gstat[n], sm[ni]);
      atomicAdd(&gstat[n + 256], sq[ni]);
    }
  }
}

// ---------------------------------------------------------------------------
// Kernel 2: stats -> scale/shift
// ---------------------------------------------------------------------------
__global__ void finalize_kernel(const float* __restrict__ gstat,
                                const float* __restrict__ gamma,
                                const float* __restrict__ beta,
                                float* __restrict__ ss) {
  int n = threadIdx.x;
  const float inv = 1.0f / (float)MOUT;
  float mu = gstat[n] * inv;
  float var = gstat[n + 256] * inv - mu * mu;
  float sc = rsqrtf(var + EPSV) * gamma[n];
  ss[n] = sc;
  ss[n + 256] = beta[n] - mu * sc;
}

// ---------------------------------------------------------------------------
// Kernel 3a: BN + ReLU from bf16 raw -> f32 out
// ---------------------------------------------------------------------------
__global__ void apply_bf16(const unsigned short* __restrict__ raw,
                           float* __restrict__ out,
                           const float* __restrict__ ss) {
  const int c0 = (threadIdx.x & 31) << 3;
  float scr[8], shr[8];
  #pragma unroll
  for (int j = 0; j < 8; ++j) { scr[j] = ss[c0 + j]; shr[j] = ss[c0 + j + 256]; }
  const long total = (long)MOUT * COUT / 8;
  const uint4* r4 = (const uint4*)raw;
  float4* o4 = (float4*)out;
  union { unsigned u; float f; } t;
  for (long i = (long)blockIdx.x * blockDim.x + threadIdx.x; i < total;
       i += (long)gridDim.x * blockDim.x) {
    uint4 v = r4[i];
    float4 a, b;
    t.u = v.x << 16;        a.x = t.f;
    t.u = v.x & 0xffff0000; a.y = t.f;
    t.u = v.y << 16;        a.z = t.f;
    t.u = v.y & 0xffff0000; a.w = t.f;
    t.u = v.z << 16;        b.x = t.f;
    t.u = v.z & 0xffff0000; b.y = t.f;
    t.u = v.w << 16;        b.z = t.f;
    t.u = v.w & 0xffff0000; b.w = t.f;
    a.x = fmaxf(fmaf(a.x, scr[0], shr[0]), 0.f);
    a.y = fmaxf(fmaf(a.y, scr[1], shr[1]), 0.f);
    a.z = fmaxf(fmaf(a.z, scr[2], shr[2]), 0.f);
    a.w = fmaxf(fmaf(a.w, scr[3], shr[3]), 0.f);
    b.x = fmaxf(fmaf(b.x, scr[4], shr[4]), 0.f);
    b.y = fmaxf(fmaf(b.y, scr[5], shr[5]), 0.f);
    b.z = fmaxf(fmaf(b.z, scr[6], shr[6]), 0.f);
    b.w = fmaxf(fmaf(b.w, scr[7], shr[7]), 0.f);
    o4[2 * i] = a;
    o4[2 * i + 1] = b;
  }
}

// ---------------------------------------------------------------------------
// Kernel 3b: in-place BN + ReLU on f32 out (fallback if ws too small)
// ---------------------------------------------------------------------------
__global__ void apply_f32(float* __restrict__ out, const float* __restrict__ ss) {
  __shared__ float sc[256], sh[256];
  sc[threadIdx.x] = ss[threadIdx.x];
  sh[threadIdx.x] = ss[threadIdx.x + 256];
  __syncthreads();
  const long total = (long)MOUT * COUT / 4;
  float4* o4 = (float4*)out;
  for (long i = (long)blockIdx.x * blockDim.x + threadIdx.x; i < total;
       i += (long)gridDim.x * blockDim.x) {
    float4 v = o4[i];
    int c = (int)(i & 63) << 2;
    v.x = fmaxf(fmaf(v.x, sc[c],     sh[c]),     0.f);
    v.y = fmaxf(fmaf(v.y, sc[c + 1], sh[c + 1]), 0.f);
    v.z = fmaxf(fmaf(v.z, sc[c + 2], sh[c + 2]), 0.f);
    v.w = fmaxf(fmaf(v.w, sc[c + 3], sh[c + 3]), 0.f);
    o4[i] = v;
  }
}

// ---------------------------------------------------------------------------
extern "C" void kernel_launch(void* const* d_in, const int* in_sizes, int n_in,
                              void* d_out, int out_size, void* d_ws, size_t ws_size,
                              hipStream_t stream) {
  const float* feats = (const float*)d_in[0];
  const float* W     = (const float*)d_in[1];
  const float* gamma = (const float*)d_in[2];
  const float* beta  = (const float*)d_in[3];
  const int*   gidx  = (const int*)d_in[4];
  float* out = (float*)d_out;

  float* gstat = (float*)d_ws;                                // 512 f32
  float* ss    = (float*)((char*)d_ws + 2048);                // 512 f32
  unsigned short* Wt = (unsigned short*)((char*)d_ws + 4096); // 512 KB
  const size_t RAW_OFF = 4096 + 512 * 1024;
  const size_t RAW_BYTES = (size_t)MOUT * COUT * 2;
  bool bf16raw = ws_size >= RAW_OFF + RAW_BYTES;
  unsigned short* raw = bf16raw ? (unsigned short*)((char*)d_ws + RAW_OFF) : nullptr;

  hipLaunchKernelGGL(prep_kernel, dim3(NT), dim3(256), 0, stream, W, Wt, gstat);
  hipLaunchKernelGGL(conv_kernel, dim3((MOUT + BM - 1) / BM), dim3(THREADS), 0,
                     stream, feats, Wt, gidx, raw, bf16raw ? nullptr : out, gstat);
  hipLaunchKernelGGL(finalize_kernel, dim3(1), dim3(256), 0, stream,
                     gstat, gamma, beta, ss);
  if (bf16raw)
    hipLaunchKernelGGL(apply_bf16, dim3(2048), dim3(256), 0, stream, raw, out, ss);
  else
    hipLaunchKernelGGL(apply_f32, dim3(2048), dim3(256), 0, stream, out, ss);
}